// Round 15
// baseline (1097.283 us; speedup 1.0000x reference)
//
#include <hip/hip_runtime.h>

typedef unsigned short u16;
typedef unsigned int u32;
typedef unsigned char u8;
typedef long f8frag;  // 64-bit: 8 fp8 elements (2 VGPRs)
typedef __bf16 bf16x8 __attribute__((ext_vector_type(8)));
typedef float f32x4 __attribute__((ext_vector_type(4)));
typedef u16 u16x4 __attribute__((ext_vector_type(4)));
typedef int i32x4 __attribute__((ext_vector_type(4)));

#define N_TW 1024
#define L_TOK 64
#define M1 (N_TW * L_TOK)

__device__ __forceinline__ u16 f2bf(float f) {
  u32 u = __builtin_bit_cast(u32, f);
  u += 0x7fffu + ((u >> 16) & 1u);
  return (u16)(u >> 16);
}
__device__ __forceinline__ float bf2f(u16 b) {
  u32 u = ((u32)b) << 16;
  return __builtin_bit_cast(float, u);
}
__device__ __forceinline__ u8 f2f8(float f) {
  return (u8)(__builtin_amdgcn_cvt_pk_fp8_f32(f, f, 0, false) & 0xff);
}
__device__ __forceinline__ void gl_lds16(const void* g, void* l) {
  __builtin_amdgcn_global_load_lds((const __attribute__((address_space(1))) u32*)g,
                                   (__attribute__((address_space(3))) u32*)l, 16, 0, 0);
}
__device__ __forceinline__ float sigf(float x) { return 1.f / (1.f + __expf(-x)); }
__device__ __forceinline__ float tanh_(float x) { return 1.f - 2.f / (__expf(2.f * x) + 1.f); }

// ---------------- fused prep: WihP(hg-order fp8) + WP4(Whh fp8 frags) + wimg bf16 + biasP ----------------
__global__ __launch_bounds__(256) void k_prep_all(
    const float* __restrict__ Wih_f, const float* __restrict__ Wih_b,
    const float* __restrict__ Whh_f, const float* __restrict__ Whh_b,
    const float* __restrict__ Wimg,
    const float* __restrict__ bih_f, const float* __restrict__ bhh_f,
    const float* __restrict__ bih_b, const float* __restrict__ bhh_b,
    u8* __restrict__ WihP, u8* __restrict__ WP4, u16* __restrict__ wimg_bf,
    float* __restrict__ biasP) {
  int bid = blockIdx.x;
  int tid = threadIdx.x;
  if (bid < 1024) {
    // WihP[dir][hb(8)][c(128)][k(512)] fp8 x16; c = hl*4+g -> row (g*256 + hb*32+hl) of Wih
    int e = (bid * 256 + tid) * 4;
    int k = e & 511;
    int c = (e >> 9) & 127;
    int hb = (e >> 16) & 7;
    int dir = e >> 19;
    int g = c & 3, h = hb * 32 + (c >> 2);
    const float* W = dir ? Wih_b : Wih_f;
    float4 v = *(const float4*)(W + (size_t)(g * 256 + h) * 512 + k);
    int w0 = __builtin_amdgcn_cvt_pk_fp8_f32(v.x * 16.f, v.y * 16.f, 0, false);
    w0 = __builtin_amdgcn_cvt_pk_fp8_f32(v.z * 16.f, v.w * 16.f, w0, true);
    *(u32*)(WihP + e) = (u32)w0;
  } else if (bid < 1536) {
    // WP4[dir][w(8)][s(8)][g(4)][c(2)][l(64)][i(8)] fp8 x16
    int e = ((bid - 1024) * 256 + tid) * 4;
    int i = e & 7, l = (e >> 3) & 63, c = (e >> 9) & 1, g = (e >> 10) & 3;
    int s = (e >> 12) & 7, w = (e >> 15) & 7, dir = e >> 18;
    int h = w * 32 + c * 16 + (l & 15);
    int k = s * 32 + ((l >> 4) << 3) + i;
    const float* W = dir ? Whh_b : Whh_f;
    float4 v = *(const float4*)(W + (size_t)(g * 256 + h) * 256 + k);
    int w0 = __builtin_amdgcn_cvt_pk_fp8_f32(v.x * 16.f, v.y * 16.f, 0, false);
    w0 = __builtin_amdgcn_cvt_pk_fp8_f32(v.z * 16.f, v.w * 16.f, w0, true);
    *(u32*)(WP4 + e) = (u32)w0;
  } else if (bid < 1792) {
    int e = ((bid - 1536) * 256 + tid) * 4;  // 262144 elems of Wimg
    float4 v = *(const float4*)(Wimg + e);
    u16x4 o;
    o.x = f2bf(v.x); o.y = f2bf(v.y); o.z = f2bf(v.z); o.w = f2bf(v.w);
    *(u16x4*)(wimg_bf + e) = o;
  } else {
    int i = (bid - 1792) * 256 + tid;  // 0..2047: biasP[dir][hb][c]
    int c = i & 127, hb = (i >> 7) & 7, dir = i >> 10;
    int g = c & 3, h = hb * 32 + (c >> 2);
    int gi = g * 256 + h;
    biasP[i] = dir ? (bih_b[gi] + bhh_b[gi]) : (bih_f[gi] + bhh_f[gi]);
  }
}

// ---------------- embedding gather + fp8 convert (x16), HW pack ----------------
__global__ __launch_bounds__(256) void k_gather8(const int* __restrict__ tok, const float* __restrict__ emb,
                                                 u8* __restrict__ x) {
  long long t = (long long)blockIdx.x * 256 + threadIdx.x;
  long long base = t * 8;
  int row = (int)(base >> 9);
  int col = (int)(base & 511);
  long long src = (long long)tok[row] * 512 + col;
  float4 a = *(const float4*)(emb + src);
  float4 b = *(const float4*)(emb + src + 4);
  int w0 = __builtin_amdgcn_cvt_pk_fp8_f32(a.x * 16.f, a.y * 16.f, 0, false);
  w0 = __builtin_amdgcn_cvt_pk_fp8_f32(a.z * 16.f, a.w * 16.f, w0, true);
  int w1 = __builtin_amdgcn_cvt_pk_fp8_f32(b.x * 16.f, b.y * 16.f, 0, false);
  w1 = __builtin_amdgcn_cvt_pk_fp8_f32(b.z * 16.f, b.w * 16.f, w1, true);
  *(u32*)(x + base) = (u32)w0;
  *(u32*)(x + base + 4) = (u32)w1;
}

// ---------------- GEMM fp8: xg = X8 @ WihP^T (hg-order cols) -> fp8 XGQ, coalesced epilogue ----------------
// bn = (dirg<<3)|hb: tile cols = hg-order c (h-local*4+g) -> per output row, 128 CONTIGUOUS XGQ bytes.
// Epilogue: acc -> f32 LDS tile (stride 68) -> cvt_pk_fp8 -> 16B coalesced stores.
__global__ __launch_bounds__(256) void k_gemm_xg9(const u8* __restrict__ X, const u8* __restrict__ WihP,
                                                  const float* __restrict__ biasP, u8* __restrict__ XGQ) {
  __shared__ __align__(16) char smem[34816];
  u8* Al = (u8*)smem;
  u8* Bl = (u8*)smem + 16384;
  float* ep = (float*)smem;
  const int tid = threadIdx.x;
  const int wv = tid >> 6, lane = tid & 63;
  const int lr = lane & 15, lh = lane >> 4;
  const int bid = blockIdx.x;
  const int local = bid >> 3;
  const int bn = local & 15;
  const int bm = (bid & 7) * 64 + (local >> 4);
  const int dirg = bn >> 3, hb = bn & 7;
  const u8* Wsrc = WihP + ((size_t)dirg * 8 + hb) * 65536;  // [c(128)][k(512)]
  f32x4 acc[2][8] = {};
  for (int kt = 0; kt < 4; ++kt) {
#pragma unroll
    for (int r = 0; r < 4; ++r) {
      int s = (r * 256 + tid) * 16;
      int row = s >> 7;
      int kb = (s & 127) ^ ((row & 7) << 4);
      gl_lds16(X + (size_t)(bm * 128 + row) * 512 + kt * 128 + kb, Al + s);
      gl_lds16(Wsrc + (size_t)row * 512 + kt * 128 + kb, Bl + s);
    }
    __syncthreads();
#pragma unroll
    for (int ks = 0; ks < 4; ++ks) {
      int off = ks * 32 + lh * 8;
      int ra = wv * 32 + lr;
      f8frag a0 = *(const f8frag*)(Al + ra * 128 + (off ^ ((ra & 7) << 4)));
      f8frag a1 = *(const f8frag*)(Al + (ra + 16) * 128 + (off ^ (((ra + 16) & 7) << 4)));
#pragma unroll
      for (int nj = 0; nj < 8; ++nj) {
        int c = nj * 16 + lr;
        f8frag b = *(const f8frag*)(Bl + c * 128 + (off ^ ((c & 7) << 4)));
        acc[0][nj] = __builtin_amdgcn_mfma_f32_16x16x32_fp8_fp8(a0, b, acc[0][nj], 0, 0, 0);
        acc[1][nj] = __builtin_amdgcn_mfma_f32_16x16x32_fp8_fp8(a1, b, acc[1][nj], 0, 0, 0);
      }
    }
    __syncthreads();
  }
  // ---- epilogue: two col-half phases through f32 LDS tile ----
  const float SD = 1.f / 256.f;
#pragma unroll 1
  for (int ch = 0; ch < 2; ++ch) {
#pragma unroll
    for (int mi = 0; mi < 2; ++mi)
#pragma unroll
      for (int njl = 0; njl < 4; ++njl) {
        int cl = njl * 16 + lr;
        int rowb = wv * 32 + mi * 16 + lh * 4;
        f32x4 v = acc[mi][ch * 4 + njl];
#pragma unroll
        for (int r = 0; r < 4; ++r) ep[(rowb + r) * 68 + cl] = v[r];
      }
    __syncthreads();
    {
      int row = tid >> 1, seg = tid & 1;
      int n = bm * 2 + (row >> 6), ltok = row & 63;
      int tt = dirg ? 63 - ltok : ltok;
      size_t rb = (((size_t)tt * 2 + dirg) * 128 + (size_t)(n >> 3)) * 8192 +
                  (size_t)(n & 7) * 1024 + hb * 128 + ch * 64 + seg * 32;
      const float* bp = biasP + (dirg * 8 + hb) * 128 + ch * 64 + seg * 32;
      i32x4 o0, o1;
#pragma unroll
      for (int j = 0; j < 8; ++j) {
        f32x4 v = *(const f32x4*)&ep[row * 68 + seg * 32 + j * 4];
        float4 bb = *(const float4*)(bp + j * 4);
        int w0 = __builtin_amdgcn_cvt_pk_fp8_f32((v[0] * SD + bb.x) * 32.f, (v[1] * SD + bb.y) * 32.f, 0, false);
        w0 = __builtin_amdgcn_cvt_pk_fp8_f32((v[2] * SD + bb.z) * 32.f, (v[3] * SD + bb.w) * 32.f, w0, true);
        if (j < 4) o0[j] = w0;
        else o1[j - 4] = w0;
      }
      *(i32x4*)(XGQ + rb) = o0;
      *(i32x4*)(XGQ + rb + 16) = o1;
    }
    __syncthreads();
  }
}

// ---------------- image mean over 49 positions ----------------
__global__ __launch_bounds__(256) void k_imgmean(const float* __restrict__ img, u16* __restrict__ o) {
  int n = blockIdx.x;
  for (int j = 0; j < 2; ++j) {
    int col = threadIdx.x + j * 256;
    const float* p = img + (long long)n * 49 * 512 + col;
    float s = 0.f;
    for (int r = 0; r < 49; ++r) s += p[r * 512];
    o[(long long)n * 512 + col] = f2bf(s * (1.f / 49.f));
  }
}

// ---------------- image GEMM (bf16, small) ----------------
__global__ __launch_bounds__(256) void k_gemm_img(const u16* __restrict__ A, const u16* __restrict__ W,
                                                  const float* __restrict__ bias, float* __restrict__ O) {
  __shared__ u16 Al[128 * 32];
  __shared__ u16 Bl[128 * 32];
  const int tid = threadIdx.x;
  const int wv = tid >> 6, lane = tid & 63;
  const int bm = blockIdx.x, bn = blockIdx.y;
  f32x4 acc[2][8] = {};
  const int lr = lane & 15, lk = (lane >> 4) * 8;
  for (int kt = 0; kt < 16; ++kt) {
    for (int i = 0; i < 2; ++i) {
      int lin = (wv * 2 + i) * 64 + lane;
      int r = lin >> 2, kc = lin & 3;
      int k = kt * 32 + kc * 8;
      gl_lds16(A + (long long)(bm * 128 + r) * 512 + k, &Al[(wv * 2 + i) * 512]);
      gl_lds16(W + (long long)(bn * 128 + r) * 512 + k, &Bl[(wv * 2 + i) * 512]);
    }
    __syncthreads();
    bf16x8 a0 = *(const bf16x8*)&Al[(wv * 32 + lr) * 32 + lk];
    bf16x8 a1 = *(const bf16x8*)&Al[(wv * 32 + 16 + lr) * 32 + lk];
    for (int nj = 0; nj < 8; ++nj) {
      bf16x8 b = *(const bf16x8*)&Bl[(nj * 16 + lr) * 32 + lk];
      acc[0][nj] = __builtin_amdgcn_mfma_f32_16x16x32_bf16(a0, b, acc[0][nj], 0, 0, 0);
      acc[1][nj] = __builtin_amdgcn_mfma_f32_16x16x32_bf16(a1, b, acc[1][nj], 0, 0, 0);
    }
    __syncthreads();
  }
  const int lh = lane >> 4;
  for (int mi = 0; mi < 2; ++mi)
    for (int nj = 0; nj < 8; ++nj) {
      int col = bn * 128 + nj * 16 + lr;
      float bv = bias[col];
      for (int r = 0; r < 4; ++r) {
        int row = bm * 128 + wv * 32 + mi * 16 + lh * 4 + r;
        O[(long long)row * 512 + col] = acc[mi][nj][r] + bv;
      }
    }
}

// ---------------- LSTM k_lstm9: fp8 resident weights + fp8 xg stream, zero-init via held zero ----------------
__global__ __launch_bounds__(512)
__attribute__((amdgpu_waves_per_eu(2, 2))) void k_lstm9(const u8* __restrict__ WP4,
                                                        const u8* __restrict__ XGQ,
                                                        float* __restrict__ Hf) {
  extern __shared__ char lds[];
  char* hbuf = lds + 131072;
  const int tid = threadIdx.x;
  const int w = tid >> 6, l = tid & 63;
  const int l15 = l & 15, l4 = l >> 4;
  const int b = blockIdx.x;
  const int dir = b >> 7;
  const int nblk = b & 127;
  const u8* wbase = WP4 + (size_t)dir * 262144 + (size_t)w * 32768;

#pragma unroll
  for (int j = 0; j < 16; ++j)
    gl_lds16(wbase + 16384 + j * 1024 + l * 16, lds + w * 16384 + j * 1024);
  f8frag breg[4][4][2];
#pragma unroll
  for (int s = 0; s < 4; ++s)
#pragma unroll
    for (int g = 0; g < 4; ++g)
#pragma unroll
      for (int c = 0; c < 2; ++c)
        breg[s][g][c] = *(const f8frag*)(wbase + ((s * 4 + g) * 2 + c) * 512 + l * 8);
  for (int i = tid; i < 2112; i += 512) ((u32*)hbuf)[i] = 0;
  const int xrow = (l4 & 1) * 4;
  const int hcol = w * 32 + (l4 >> 1) * 16 + l15;
  int xv[4];
  {
    const u8* xb = XGQ + (((size_t)dir) * 128 + nblk) * 8192 + hcol * 4;
#pragma unroll
    for (int r = 0; r < 4; ++r) xv[r] = *(const int*)(xb + (xrow + r) * 1024);
  }
  __syncthreads();

  float cst[4] = {0.f, 0.f, 0.f, 0.f};
  f32x4 z4 = {0.f, 0.f, 0.f, 0.f};
  asm volatile("" : "+v"(z4));  // pin zero in VGPRs (hoisted out of the loop)
  const float S = 1.f / 512.f;
  const float SX = 1.f / 32.f;
#pragma unroll 1
  for (int t = 0; t < 64; ++t) {
    const char* hrd = hbuf + (t & 1) * 4224;
    char* hwr = hbuf + ((t + 1) & 1) * 4224;
    f32x4 acc[4][2];
    // ---- slab 0: init acc directly from MFMA with held zero C ----
    {
      f8frag a = *(const f8frag*)(hrd + l15 * 264 + l4 * 8);
#pragma unroll
      for (int g = 0; g < 4; ++g) {
        acc[g][0] = __builtin_amdgcn_mfma_f32_16x16x32_fp8_fp8(a, breg[0][g][0], z4, 0, 0, 0);
        acc[g][1] = __builtin_amdgcn_mfma_f32_16x16x32_fp8_fp8(a, breg[0][g][1], z4, 0, 0, 0);
      }
    }
#pragma unroll
    for (int s = 1; s < 4; ++s) {
      f8frag a = *(const f8frag*)(hrd + l15 * 264 + s * 32 + l4 * 8);
#pragma unroll
      for (int g = 0; g < 4; ++g) {
        acc[g][0] = __builtin_amdgcn_mfma_f32_16x16x32_fp8_fp8(a, breg[s][g][0], acc[g][0], 0, 0, 0);
        acc[g][1] = __builtin_amdgcn_mfma_f32_16x16x32_fp8_fp8(a, breg[s][g][1], acc[g][1], 0, 0, 0);
      }
    }
#pragma unroll
    for (int sl = 0; sl < 4; ++sl) {
      f8frag a = *(const f8frag*)(hrd + l15 * 264 + (4 + sl) * 32 + l4 * 8);
#pragma unroll
      for (int g = 0; g < 4; ++g)
#pragma unroll
        for (int c = 0; c < 2; ++c) {
          f8frag bb = *(const f8frag*)(lds + w * 16384 + ((sl * 4 + g) * 2 + c) * 512 + l * 8);
          acc[g][c] = __builtin_amdgcn_mfma_f32_16x16x32_fp8_fp8(a, bb, acc[g][c], 0, 0, 0);
        }
    }
#pragma unroll
    for (int r = 0; r < 4; ++r) {
      float z[4];
#pragma unroll
      for (int g = 0; g < 4; ++g) {
        u32 x = __builtin_bit_cast(u32, acc[g][0][r]);
        u32 y = __builtin_bit_cast(u32, acc[g][1][r]);
        asm("v_permlane32_swap_b32 %0, %1" : "+v"(x), "+v"(y));
        z[g] = __builtin_bit_cast(float, x);
      }
      float gi = z[0] * S + __builtin_amdgcn_cvt_f32_fp8(xv[r], 0) * SX;
      float gf = z[1] * S + __builtin_amdgcn_cvt_f32_fp8(xv[r], 1) * SX;
      float gg = z[2] * S + __builtin_amdgcn_cvt_f32_fp8(xv[r], 2) * SX;
      float go = z[3] * S + __builtin_amdgcn_cvt_f32_fp8(xv[r], 3) * SX;
      float cn = sigf(gf) * cst[r] + sigf(gi) * tanh_(gg);
      cst[r] = cn;
      float hn = sigf(go) * tanh_(cn);
      int row = xrow + r;
      if (t < 63) {
        *(u8*)(hwr + row * 264 + hcol) = f2f8(hn * 32.f);
      } else {
        Hf[(size_t)(dir * 1024 + nblk * 8 + row) * 256 + hcol] = hn;
      }
    }
    {
      int tn = (t < 63) ? t + 1 : 63;
      const u8* xb = XGQ + (((size_t)tn * 2 + dir) * 128 + nblk) * 8192 + hcol * 4;
#pragma unroll
      for (int r = 0; r < 4; ++r) xv[r] = *(const int*)(xb + (xrow + r) * 1024);
    }
    asm volatile("s_waitcnt lgkmcnt(0)" ::: "memory");
    __builtin_amdgcn_sched_barrier(0);
    __builtin_amdgcn_s_barrier();
    __builtin_amdgcn_sched_barrier(0);
  }
}

// ---------------- attention fusion + mean over tweets ----------------
__global__ __launch_bounds__(256) void k_fusion(const float* __restrict__ Hf, const float* __restrict__ IH,
                                                const float* __restrict__ WT, const float* __restrict__ WI,
                                                float* __restrict__ msum) {
  int wv = threadIdx.x >> 6, lane = threadIdx.x & 63;
  float facc[8] = {0.f, 0.f, 0.f, 0.f, 0.f, 0.f, 0.f, 0.f};
  for (int p = 0; p < 8; ++p) {
    int n = blockIdx.x * 32 + wv * 8 + p;
    float th[8], ih[8];
    float ts = 0.f, is = 0.f;
    for (int j = 0; j < 8; ++j) {
      int e = lane * 8 + j;
      float tv = (e < 256) ? Hf[(long long)n * 256 + e] : Hf[(long long)(1024 + n) * 256 + (e - 256)];
      float iv = IH[(long long)n * 512 + e];
      th[j] = tv; ih[j] = iv;
      ts += tv * WT[e];
      is += iv * WI[e];
    }
    for (int off = 32; off > 0; off >>= 1) {
      ts += __shfl_down(ts, off);
      is += __shfl_down(is, off);
    }
    ts = __shfl(ts, 0);
    is = __shfl(is, 0);
    float a0 = 1.f / (1.f + __expf(is - ts));
    float a1 = 1.f - a0;
    for (int j = 0; j < 8; ++j) facc[j] += a0 * th[j] + a1 * ih[j];
  }
  for (int j = 0; j < 8; ++j) atomicAdd(&msum[lane * 8 + j], facc[j]);
}

// ---------------- classifier MLP ----------------
__global__ __launch_bounds__(256) void k_cls(const float* __restrict__ msum, const float* __restrict__ Wc1,
                                             const float* __restrict__ bc1, const float* __restrict__ Wc2,
                                             const float* __restrict__ bc2, float* __restrict__ out) {
  __shared__ float mf[512];
  __shared__ float hdd[512];
  __shared__ float red[2][256];
  int tid = threadIdx.x;
  for (int j = tid; j < 512; j += 256) mf[j] = msum[j] * (1.f / 1024.f);
  __syncthreads();
  for (int j = tid; j < 512; j += 256) {
    const float* wr = Wc1 + (long long)j * 512;
    float s = bc1[j];
    for (int k = 0; k < 512; ++k) s += mf[k] * wr[k];
    hdd[j] = fmaxf(s, 0.f);
  }
  __syncthreads();
  float s0 = 0.f, s1 = 0.f;
  for (int k = tid; k < 512; k += 256) {
    s0 += hdd[k] * Wc2[k];
    s1 += hdd[k] * Wc2[512 + k];
  }
  red[0][tid] = s0;
  red[1][tid] = s1;
  __syncthreads();
  if (tid < 2) {
    float s = 0.f;
    for (int k = 0; k < 256; ++k) s += red[tid][k];
    out[tid] = s + bc2[tid];
  }
}

extern "C" void kernel_launch(void* const* d_in, const int* in_sizes, int n_in,
                              void* d_out, int out_size, void* d_ws, size_t ws_size,
                              hipStream_t stream) {
  const int* tokens = (const int*)d_in[0];
  const float* images = (const float*)d_in[1];
  const float* embed = (const float*)d_in[2];
  const float* Wih_f = (const float*)d_in[3];
  const float* Whh_f = (const float*)d_in[4];
  const float* bih_f = (const float*)d_in[5];
  const float* bhh_f = (const float*)d_in[6];
  const float* Wih_b = (const float*)d_in[7];
  const float* Whh_b = (const float*)d_in[8];
  const float* bih_b = (const float*)d_in[9];
  const float* bhh_b = (const float*)d_in[10];
  const float* Wimg = (const float*)d_in[11];
  const float* bimg = (const float*)d_in[12];
  const float* W_T = (const float*)d_in[13];
  const float* W_I = (const float*)d_in[14];
  const float* Wc1 = (const float*)d_in[15];
  const float* bc1 = (const float*)d_in[16];
  const float* Wc2 = (const float*)d_in[17];
  const float* bc2 = (const float*)d_in[18];
  float* out = (float*)d_out;

  char* ws = (char*)d_ws;
  size_t off = 0;
  auto alloc = [&](size_t bytes) -> void* {
    void* p = ws + off;
    off += (bytes + 255) & ~(size_t)255;
    return p;
  };
  u8* x8 = (u8*)alloc((size_t)M1 * 512);          // 32 MiB fp8 X
  u8* xgq = (u8*)alloc((size_t)M1 * 2048);        // 128 MiB fp8 XGQ (L3-resident)
  u8* wihP = (u8*)alloc((size_t)2 * 524288);      // 1 MiB fp8 hg-order Wih
  u8* wp = (u8*)alloc((size_t)2 * 262144);        // 512 KiB fp8 fragment-packed Whh
  u16* wimg_bf = (u16*)alloc((size_t)512 * 512 * 2);
  float* biasP = (float*)alloc((size_t)2048 * 4);
  float* hf32 = (float*)alloc((size_t)2048 * 256 * 4);
  u16* im_bf = (u16*)alloc((size_t)1024 * 512 * 2);
  float* im_h = (float*)alloc((size_t)1024 * 512 * 4);
  float* msum = (float*)alloc((size_t)512 * 4);

  hipMemsetAsync(msum, 0, (size_t)512 * 4, stream);

  k_prep_all<<<1800, 256, 0, stream>>>(Wih_f, Wih_b, Whh_f, Whh_b, Wimg,
                                       bih_f, bhh_f, bih_b, bhh_b,
                                       wihP, wp, wimg_bf, biasP);

  k_gather8<<<16384, 256, 0, stream>>>(tokens, embed, x8);
  k_gemm_xg9<<<8192, 256, 0, stream>>>(x8, wihP, biasP, xgq);

  k_imgmean<<<1024, 256, 0, stream>>>(images, im_bf);
  k_gemm_img<<<dim3(8, 4), 256, 0, stream>>>(im_bf, wimg_bf, bimg, im_h);

  hipFuncSetAttribute((const void*)k_lstm9, hipFuncAttributeMaxDynamicSharedMemorySize, 139520);
  k_lstm9<<<256, 512, 139520, stream>>>(wp, xgq, hf32);

  k_fusion<<<32, 256, 0, stream>>>(hf32, im_h, W_T, W_I, msum);
  k_cls<<<1, 256, 0, stream>>>(msum, Wc1, bc1, Wc2, bc2, out);
}

// Round 16
// 488.753 us; speedup vs baseline: 2.2451x; 2.2451x over previous
//
#include <hip/hip_runtime.h>

typedef unsigned short u16;
typedef unsigned int u32;
typedef unsigned char u8;
typedef long f8frag;  // 64-bit: 8 fp8 elements (2 VGPRs)
typedef __bf16 bf16x8 __attribute__((ext_vector_type(8)));
typedef float f32x4 __attribute__((ext_vector_type(4)));
typedef u16 u16x4 __attribute__((ext_vector_type(4)));
typedef int i32x4 __attribute__((ext_vector_type(4)));

#define N_TW 1024
#define L_TOK 64
#define M1 (N_TW * L_TOK)

__device__ __forceinline__ u16 f2bf(float f) {
  u32 u = __builtin_bit_cast(u32, f);
  u += 0x7fffu + ((u >> 16) & 1u);
  return (u16)(u >> 16);
}
__device__ __forceinline__ float bf2f(u16 b) {
  u32 u = ((u32)b) << 16;
  return __builtin_bit_cast(float, u);
}
__device__ __forceinline__ u8 f2f8(float f) {
  return (u8)(__builtin_amdgcn_cvt_pk_fp8_f32(f, f, 0, false) & 0xff);
}
__device__ __forceinline__ void gl_lds16(const void* g, void* l) {
  __builtin_amdgcn_global_load_lds((const __attribute__((address_space(1))) u32*)g,
                                   (__attribute__((address_space(3))) u32*)l, 16, 0, 0);
}
__device__ __forceinline__ float sigf(float x) { return 1.f / (1.f + __expf(-x)); }
__device__ __forceinline__ float tanh_(float x) { return 1.f - 2.f / (__expf(2.f * x) + 1.f); }

// ---------------- fused prep (1 launch): wih8 (row-major fp8 x16) + WP4 + wimg bf16 + bias_a ----------------
// blocks 0..1023: Wih fwd/bwd -> wih8[dir*524288 + ...]; 1024..1535: WP4; 1536..1791: Wimg; 1792..1799: bias.
__global__ __launch_bounds__(256) void k_prep_all(
    const float* __restrict__ Wih_f, const float* __restrict__ Wih_b,
    const float* __restrict__ Whh_f, const float* __restrict__ Whh_b,
    const float* __restrict__ Wimg,
    const float* __restrict__ bih_f, const float* __restrict__ bhh_f,
    const float* __restrict__ bih_b, const float* __restrict__ bhh_b,
    u8* __restrict__ wih8, u8* __restrict__ WP4, u16* __restrict__ wimg_bf,
    float* __restrict__ bias_a) {
  int bid = blockIdx.x;
  int tid = threadIdx.x;
  if (bid < 1024) {
    int dir = bid >> 9;
    int e = ((bid & 511) * 256 + tid) * 4;  // 0..524287
    const float* W = dir ? Wih_b : Wih_f;
    float4 v = *(const float4*)(W + e);
    int w0 = __builtin_amdgcn_cvt_pk_fp8_f32(v.x * 16.f, v.y * 16.f, 0, false);
    w0 = __builtin_amdgcn_cvt_pk_fp8_f32(v.z * 16.f, v.w * 16.f, w0, true);
    *(u32*)(wih8 + (size_t)dir * 524288 + e) = (u32)w0;
  } else if (bid < 1536) {
    // WP4[dir][w(8)][s(8)][g(4)][c(2)][l(64)][i(8)] fp8 x16
    int e = ((bid - 1024) * 256 + tid) * 4;
    int base = e;
#pragma unroll
    for (int q = 0; q < 1; ++q) {}  // keep structure simple
    int i0 = base;
    u8 ob[4];
#pragma unroll
    for (int d = 0; d < 4; ++d) {
      int e1 = i0 + d;
      int i = e1 & 7, l = (e1 >> 3) & 63, c = (e1 >> 9) & 1, g = (e1 >> 10) & 3;
      int s = (e1 >> 12) & 7, w = (e1 >> 15) & 7, dir = e1 >> 18;
      int h = w * 32 + c * 16 + (l & 15);
      int k = s * 32 + ((l >> 4) << 3) + i;
      const float* W = dir ? Whh_b : Whh_f;
      ob[d] = f2f8(W[(size_t)(g * 256 + h) * 256 + k] * 16.f);
    }
    *(u32*)(WP4 + i0) = (u32)ob[0] | ((u32)ob[1] << 8) | ((u32)ob[2] << 16) | ((u32)ob[3] << 24);
  } else if (bid < 1792) {
    int e = ((bid - 1536) * 256 + tid) * 4;  // 262144 elems of Wimg
    float4 v = *(const float4*)(Wimg + e);
    u16x4 o;
    o.x = f2bf(v.x); o.y = f2bf(v.y); o.z = f2bf(v.z); o.w = f2bf(v.w);
    *(u16x4*)(wimg_bf + e) = o;
  } else {
    int i = (bid - 1792) * 256 + tid;  // 0..2047
    int dir = i >> 10, gi = i & 1023;
    bias_a[i] = dir ? (bih_b[gi] + bhh_b[gi]) : (bih_f[gi] + bhh_f[gi]);
  }
}

// ---------------- embedding gather + fp8 convert (x16), HW pack ----------------
__global__ __launch_bounds__(256) void k_gather8(const int* __restrict__ tok, const float* __restrict__ emb,
                                                 u8* __restrict__ x) {
  long long t = (long long)blockIdx.x * 256 + threadIdx.x;
  long long base = t * 8;
  int row = (int)(base >> 9);
  int col = (int)(base & 511);
  long long src = (long long)tok[row] * 512 + col;
  float4 a = *(const float4*)(emb + src);
  float4 b = *(const float4*)(emb + src + 4);
  int w0 = __builtin_amdgcn_cvt_pk_fp8_f32(a.x * 16.f, a.y * 16.f, 0, false);
  w0 = __builtin_amdgcn_cvt_pk_fp8_f32(a.z * 16.f, a.w * 16.f, w0, true);
  int w1 = __builtin_amdgcn_cvt_pk_fp8_f32(b.x * 16.f, b.y * 16.f, 0, false);
  w1 = __builtin_amdgcn_cvt_pk_fp8_f32(b.z * 16.f, b.w * 16.f, w1, true);
  *(u32*)(x + base) = (u32)w0;
  *(u32*)(x + base + 4) = (u32)w1;
}

// ---------------- GEMM fp8 (r14-proven): xg = X8 @ wih8^T (x1/256) + bias -> fp8 x32, XGQ8 ----------------
// XGQ8[t][dir][nblk(128)][nrow(8)][h(256)*4+g] u8. Epilogue: per-lane scattered 1B stores,
// wave-level h-contiguous -> L2 merges into full lines (measured r14: WRITE 262MB, no amplification).
__global__ __launch_bounds__(256) void k_gemm_xg8(const u8* __restrict__ X, const u8* __restrict__ W,
                                                  const float* __restrict__ bias, u8* __restrict__ XGQ) {
  __shared__ u8 Al[128 * 128];  // 16 KB
  __shared__ u8 Bl[128 * 128];
  const int tid = threadIdx.x;
  const int wv = tid >> 6, lane = tid & 63;
  const int lr = lane & 15, lh = lane >> 4;
  const int bid = blockIdx.x;
  const int local = bid >> 3;
  const int bn = local & 15;
  const int bm = (bid & 7) * 64 + (local >> 4);
  f32x4 acc[2][8] = {};
  for (int kt = 0; kt < 4; ++kt) {
#pragma unroll
    for (int r = 0; r < 4; ++r) {
      int s = (r * 256 + tid) * 16;
      int row = s >> 7;
      int kb = (s & 127) ^ ((row & 7) << 4);  // pre-swizzled global source (rule 21)
      gl_lds16(X + (size_t)(bm * 128 + row) * 512 + kt * 128 + kb, Al + s);
      gl_lds16(W + (size_t)(bn * 128 + row) * 512 + kt * 128 + kb, Bl + s);
    }
    __syncthreads();
#pragma unroll
    for (int ks = 0; ks < 4; ++ks) {
      int off = ks * 32 + lh * 8;
      int ra = wv * 32 + lr;
      f8frag a0 = *(const f8frag*)(Al + ra * 128 + (off ^ ((ra & 7) << 4)));
      f8frag a1 = *(const f8frag*)(Al + (ra + 16) * 128 + (off ^ (((ra + 16) & 7) << 4)));
#pragma unroll
      for (int nj = 0; nj < 8; ++nj) {
        int c = nj * 16 + lr;
        f8frag b = *(const f8frag*)(Bl + c * 128 + (off ^ ((c & 7) << 4)));
        acc[0][nj] = __builtin_amdgcn_mfma_f32_16x16x32_fp8_fp8(a0, b, acc[0][nj], 0, 0, 0);
        acc[1][nj] = __builtin_amdgcn_mfma_f32_16x16x32_fp8_fp8(a1, b, acc[1][nj], 0, 0, 0);
      }
    }
    __syncthreads();
  }
  const float SD = 1.f / 256.f;
#pragma unroll
  for (int mi = 0; mi < 2; ++mi)
#pragma unroll
    for (int nj = 0; nj < 8; ++nj) {
      int col = bn * 128 + nj * 16 + lr;
      float bv = bias[col];
      int dirg = col >> 10, gg = (col >> 8) & 3, h = col & 255;
#pragma unroll
      for (int r = 0; r < 4; ++r) {
        int row = bm * 128 + wv * 32 + mi * 16 + lh * 4 + r;
        int n = row >> 6, ltok = row & 63;
        int tt = dirg ? (63 - ltok) : ltok;
        size_t idx = (((size_t)tt * 2 + dirg) * 128 + (n >> 3)) * 8192 + (size_t)(n & 7) * 1024 + h * 4 + gg;
        XGQ[idx] = f2f8((acc[mi][nj][r] * SD + bv) * 32.f);
      }
    }
}

// ---------------- image mean over 49 positions ----------------
__global__ __launch_bounds__(256) void k_imgmean(const float* __restrict__ img, u16* __restrict__ o) {
  int n = blockIdx.x;
  for (int j = 0; j < 2; ++j) {
    int col = threadIdx.x + j * 256;
    const float* p = img + (long long)n * 49 * 512 + col;
    float s = 0.f;
    for (int r = 0; r < 49; ++r) s += p[r * 512];
    o[(long long)n * 512 + col] = f2bf(s * (1.f / 49.f));
  }
}

// ---------------- image GEMM (bf16, small) ----------------
__global__ __launch_bounds__(256) void k_gemm_img(const u16* __restrict__ A, const u16* __restrict__ W,
                                                  const float* __restrict__ bias, float* __restrict__ O) {
  __shared__ u16 Al[128 * 32];
  __shared__ u16 Bl[128 * 32];
  const int tid = threadIdx.x;
  const int wv = tid >> 6, lane = tid & 63;
  const int bm = blockIdx.x, bn = blockIdx.y;
  f32x4 acc[2][8] = {};
  const int lr = lane & 15, lk = (lane >> 4) * 8;
  for (int kt = 0; kt < 16; ++kt) {
    for (int i = 0; i < 2; ++i) {
      int lin = (wv * 2 + i) * 64 + lane;
      int r = lin >> 2, kc = lin & 3;
      int k = kt * 32 + kc * 8;
      gl_lds16(A + (long long)(bm * 128 + r) * 512 + k, &Al[(wv * 2 + i) * 512]);
      gl_lds16(W + (long long)(bn * 128 + r) * 512 + k, &Bl[(wv * 2 + i) * 512]);
    }
    __syncthreads();
    bf16x8 a0 = *(const bf16x8*)&Al[(wv * 32 + lr) * 32 + lk];
    bf16x8 a1 = *(const bf16x8*)&Al[(wv * 32 + 16 + lr) * 32 + lk];
    for (int nj = 0; nj < 8; ++nj) {
      bf16x8 b = *(const bf16x8*)&Bl[(nj * 16 + lr) * 32 + lk];
      acc[0][nj] = __builtin_amdgcn_mfma_f32_16x16x32_bf16(a0, b, acc[0][nj], 0, 0, 0);
      acc[1][nj] = __builtin_amdgcn_mfma_f32_16x16x32_bf16(a1, b, acc[1][nj], 0, 0, 0);
    }
    __syncthreads();
  }
  const int lh = lane >> 4;
  for (int mi = 0; mi < 2; ++mi)
    for (int nj = 0; nj < 8; ++nj) {
      int col = bn * 128 + nj * 16 + lr;
      float bv = bias[col];
      for (int r = 0; r < 4; ++r) {
        int row = bm * 128 + wv * 32 + mi * 16 + lh * 4 + r;
        O[(long long)row * 512 + col] = acc[mi][nj][r] + bv;
      }
    }
}

// ---------------- LSTM k_lstm9: fp8 resident weights + fp8 xg stream, MFMA-zero-init ----------------
__global__ __launch_bounds__(512)
__attribute__((amdgpu_waves_per_eu(2, 2))) void k_lstm9(const u8* __restrict__ WP4,
                                                        const u8* __restrict__ XGQ,
                                                        float* __restrict__ Hf) {
  extern __shared__ char lds[];
  char* hbuf = lds + 131072;
  const int tid = threadIdx.x;
  const int w = tid >> 6, l = tid & 63;
  const int l15 = l & 15, l4 = l >> 4;
  const int b = blockIdx.x;
  const int dir = b >> 7;
  const int nblk = b & 127;
  const u8* wbase = WP4 + (size_t)dir * 262144 + (size_t)w * 32768;

#pragma unroll
  for (int j = 0; j < 16; ++j)
    gl_lds16(wbase + 16384 + j * 1024 + l * 16, lds + w * 16384 + j * 1024);
  f8frag breg[4][4][2];
#pragma unroll
  for (int s = 0; s < 4; ++s)
#pragma unroll
    for (int g = 0; g < 4; ++g)
#pragma unroll
      for (int c = 0; c < 2; ++c)
        breg[s][g][c] = *(const f8frag*)(wbase + ((s * 4 + g) * 2 + c) * 512 + l * 8);
  for (int i = tid; i < 2112; i += 512) ((u32*)hbuf)[i] = 0;
  const int xrow = (l4 & 1) * 4;
  const int hcol = w * 32 + (l4 >> 1) * 16 + l15;
  int xv[4];
  {
    const u8* xb = XGQ + (((size_t)dir) * 128 + nblk) * 8192 + hcol * 4;
#pragma unroll
    for (int r = 0; r < 4; ++r) xv[r] = *(const int*)(xb + (xrow + r) * 1024);
  }
  __syncthreads();

  float cst[4] = {0.f, 0.f, 0.f, 0.f};
  f32x4 z4 = {0.f, 0.f, 0.f, 0.f};
  asm volatile("" : "+v"(z4));  // pin zero in VGPRs
  const float S = 1.f / 512.f;
  const float SX = 1.f / 32.f;
#pragma unroll 1
  for (int t = 0; t < 64; ++t) {
    const char* hrd = hbuf + (t & 1) * 4224;
    char* hwr = hbuf + ((t + 1) & 1) * 4224;
    f32x4 acc[4][2];
    {
      f8frag a = *(const f8frag*)(hrd + l15 * 264 + l4 * 8);
#pragma unroll
      for (int g = 0; g < 4; ++g) {
        acc[g][0] = __builtin_amdgcn_mfma_f32_16x16x32_fp8_fp8(a, breg[0][g][0], z4, 0, 0, 0);
        acc[g][1] = __builtin_amdgcn_mfma_f32_16x16x32_fp8_fp8(a, breg[0][g][1], z4, 0, 0, 0);
      }
    }
#pragma unroll
    for (int s = 1; s < 4; ++s) {
      f8frag a = *(const f8frag*)(hrd + l15 * 264 + s * 32 + l4 * 8);
#pragma unroll
      for (int g = 0; g < 4; ++g) {
        acc[g][0] = __builtin_amdgcn_mfma_f32_16x16x32_fp8_fp8(a, breg[s][g][0], acc[g][0], 0, 0, 0);
        acc[g][1] = __builtin_amdgcn_mfma_f32_16x16x32_fp8_fp8(a, breg[s][g][1], acc[g][1], 0, 0, 0);
      }
    }
#pragma unroll
    for (int sl = 0; sl < 4; ++sl) {
      f8frag a = *(const f8frag*)(hrd + l15 * 264 + (4 + sl) * 32 + l4 * 8);
#pragma unroll
      for (int g = 0; g < 4; ++g)
#pragma unroll
        for (int c = 0; c < 2; ++c) {
          f8frag bb = *(const f8frag*)(lds + w * 16384 + ((sl * 4 + g) * 2 + c) * 512 + l * 8);
          acc[g][c] = __builtin_amdgcn_mfma_f32_16x16x32_fp8_fp8(a, bb, acc[g][c], 0, 0, 0);
        }
    }
#pragma unroll
    for (int r = 0; r < 4; ++r) {
      float z[4];
#pragma unroll
      for (int g = 0; g < 4; ++g) {
        u32 x = __builtin_bit_cast(u32, acc[g][0][r]);
        u32 y = __builtin_bit_cast(u32, acc[g][1][r]);
        asm("v_permlane32_swap_b32 %0, %1" : "+v"(x), "+v"(y));
        z[g] = __builtin_bit_cast(float, x);
      }
      float gi = z[0] * S + __builtin_amdgcn_cvt_f32_fp8(xv[r], 0) * SX;
      float gf = z[1] * S + __builtin_amdgcn_cvt_f32_fp8(xv[r], 1) * SX;
      float gg = z[2] * S + __builtin_amdgcn_cvt_f32_fp8(xv[r], 2) * SX;
      float go = z[3] * S + __builtin_amdgcn_cvt_f32_fp8(xv[r], 3) * SX;
      float cn = sigf(gf) * cst[r] + sigf(gi) * tanh_(gg);
      cst[r] = cn;
      float hn = sigf(go) * tanh_(cn);
      int row = xrow + r;
      if (t < 63) {
        *(u8*)(hwr + row * 264 + hcol) = f2f8(hn * 32.f);
      } else {
        Hf[(size_t)(dir * 1024 + nblk * 8 + row) * 256 + hcol] = hn;
      }
    }
    {
      int tn = (t < 63) ? t + 1 : 63;
      const u8* xb = XGQ + (((size_t)tn * 2 + dir) * 128 + nblk) * 8192 + hcol * 4;
#pragma unroll
      for (int r = 0; r < 4; ++r) xv[r] = *(const int*)(xb + (xrow + r) * 1024);
    }
    asm volatile("s_waitcnt lgkmcnt(0)" ::: "memory");
    __builtin_amdgcn_sched_barrier(0);
    __builtin_amdgcn_s_barrier();
    __builtin_amdgcn_sched_barrier(0);
  }
}

// ---------------- attention fusion + mean over tweets ----------------
__global__ __launch_bounds__(256) void k_fusion(const float* __restrict__ Hf, const float* __restrict__ IH,
                                                const float* __restrict__ WT, const float* __restrict__ WI,
                                                float* __restrict__ msum) {
  int wv = threadIdx.x >> 6, lane = threadIdx.x & 63;
  float facc[8] = {0.f, 0.f, 0.f, 0.f, 0.f, 0.f, 0.f, 0.f};
  for (int p = 0; p < 8; ++p) {
    int n = blockIdx.x * 32 + wv * 8 + p;
    float th[8], ih[8];
    float ts = 0.f, is = 0.f;
    for (int j = 0; j < 8; ++j) {
      int e = lane * 8 + j;
      float tv = (e < 256) ? Hf[(long long)n * 256 + e] : Hf[(long long)(1024 + n) * 256 + (e - 256)];
      float iv = IH[(long long)n * 512 + e];
      th[j] = tv; ih[j] = iv;
      ts += tv * WT[e];
      is += iv * WI[e];
    }
    for (int off = 32; off > 0; off >>= 1) {
      ts += __shfl_down(ts, off);
      is += __shfl_down(is, off);
    }
    ts = __shfl(ts, 0);
    is = __shfl(is, 0);
    float a0 = 1.f / (1.f + __expf(is - ts));
    float a1 = 1.f - a0;
    for (int j = 0; j < 8; ++j) facc[j] += a0 * th[j] + a1 * ih[j];
  }
  for (int j = 0; j < 8; ++j) atomicAdd(&msum[lane * 8 + j], facc[j]);
}

// ---------------- classifier MLP ----------------
__global__ __launch_bounds__(256) void k_cls(const float* __restrict__ msum, const float* __restrict__ Wc1,
                                             const float* __restrict__ bc1, const float* __restrict__ Wc2,
                                             const float* __restrict__ bc2, float* __restrict__ out) {
  __shared__ float mf[512];
  __shared__ float hdd[512];
  __shared__ float red[2][256];
  int tid = threadIdx.x;
  for (int j = tid; j < 512; j += 256) mf[j] = msum[j] * (1.f / 1024.f);
  __syncthreads();
  for (int j = tid; j < 512; j += 256) {
    const float* wr = Wc1 + (long long)j * 512;
    float s = bc1[j];
    for (int k = 0; k < 512; ++k) s += mf[k] * wr[k];
    hdd[j] = fmaxf(s, 0.f);
  }
  __syncthreads();
  float s0 = 0.f, s1 = 0.f;
  for (int k = tid; k < 512; k += 256) {
    s0 += hdd[k] * Wc2[k];
    s1 += hdd[k] * Wc2[512 + k];
  }
  red[0][tid] = s0;
  red[1][tid] = s1;
  __syncthreads();
  if (tid < 2) {
    float s = 0.f;
    for (int k = 0; k < 256; ++k) s += red[tid][k];
    out[tid] = s + bc2[tid];
  }
}

extern "C" void kernel_launch(void* const* d_in, const int* in_sizes, int n_in,
                              void* d_out, int out_size, void* d_ws, size_t ws_size,
                              hipStream_t stream) {
  const int* tokens = (const int*)d_in[0];
  const float* images = (const float*)d_in[1];
  const float* embed = (const float*)d_in[2];
  const float* Wih_f = (const float*)d_in[3];
  const float* Whh_f = (const float*)d_in[4];
  const float* bih_f = (const float*)d_in[5];
  const float* bhh_f = (const float*)d_in[6];
  const float* Wih_b = (const float*)d_in[7];
  const float* Whh_b = (const float*)d_in[8];
  const float* bih_b = (const float*)d_in[9];
  const float* bhh_b = (const float*)d_in[10];
  const float* Wimg = (const float*)d_in[11];
  const float* bimg = (const float*)d_in[12];
  const float* W_T = (const float*)d_in[13];
  const float* W_I = (const float*)d_in[14];
  const float* Wc1 = (const float*)d_in[15];
  const float* bc1 = (const float*)d_in[16];
  const float* Wc2 = (const float*)d_in[17];
  const float* bc2 = (const float*)d_in[18];
  float* out = (float*)d_out;

  char* ws = (char*)d_ws;
  size_t off = 0;
  auto alloc = [&](size_t bytes) -> void* {
    void* p = ws + off;
    off += (bytes + 255) & ~(size_t)255;
    return p;
  };
  u8* x8 = (u8*)alloc((size_t)M1 * 512);          // 32 MiB fp8 X
  u8* xgq = (u8*)alloc((size_t)M1 * 2048);        // 128 MiB fp8 XGQ (L3-resident)
  u8* wih8 = (u8*)alloc((size_t)2 * 524288);      // 1 MiB fp8 Wih (row-major)
  u8* wp = (u8*)alloc((size_t)2 * 262144);        // 512 KiB fp8 fragment-packed Whh
  u16* wimg_bf = (u16*)alloc((size_t)512 * 512 * 2);
  float* bias_a = (float*)alloc((size_t)2048 * 4);
  float* hf32 = (float*)alloc((size_t)2048 * 256 * 4);
  u16* im_bf = (u16*)alloc((size_t)1024 * 512 * 2);
  float* im_h = (float*)alloc((size_t)1024 * 512 * 4);
  float* msum = (float*)alloc((size_t)512 * 4);

  hipMemsetAsync(msum, 0, (size_t)512 * 4, stream);

  k_prep_all<<<1800, 256, 0, stream>>>(Wih_f, Wih_b, Whh_f, Whh_b, Wimg,
                                       bih_f, bhh_f, bih_b, bhh_b,
                                       wih8, wp, wimg_bf, bias_a);

  k_gather8<<<16384, 256, 0, stream>>>(tokens, embed, x8);
  k_gemm_xg8<<<8192, 256, 0, stream>>>(x8, wih8, bias_a, xgq);

  k_imgmean<<<1024, 256, 0, stream>>>(images, im_bf);
  k_gemm_img<<<dim3(8, 4), 256, 0, stream>>>(im_bf, wimg_bf, bimg, im_h);

  hipFuncSetAttribute((const void*)k_lstm9, hipFuncAttributeMaxDynamicSharedMemorySize, 139520);
  k_lstm9<<<256, 512, 139520, stream>>>(wp, xgq, hf32);

  k_fusion<<<32, 256, 0, stream>>>(hf32, im_h, W_T, W_I, msum);
  k_cls<<<1, 256, 0, stream>>>(msum, Wc1, bc1, Wc2, bc2, out);
}

// Round 17
// 356.064 us; speedup vs baseline: 3.0817x; 1.3727x over previous
//
#include <hip/hip_runtime.h>

typedef unsigned short u16;
typedef unsigned int u32;
typedef unsigned char u8;
typedef long f8frag;  // 64-bit: 8 fp8 elements (2 VGPRs)
typedef __bf16 bf16x8 __attribute__((ext_vector_type(8)));
typedef float f32x4 __attribute__((ext_vector_type(4)));
typedef u16 u16x4 __attribute__((ext_vector_type(4)));
typedef int i32x4 __attribute__((ext_vector_type(4)));

#define N_TW 1024
#define L_TOK 64
#define M1 (N_TW * L_TOK)

__device__ __forceinline__ u16 f2bf(float f) {
  u32 u = __builtin_bit_cast(u32, f);
  u += 0x7fffu + ((u >> 16) & 1u);
  return (u16)(u >> 16);
}
__device__ __forceinline__ float bf2f(u16 b) {
  u32 u = ((u32)b) << 16;
  return __builtin_bit_cast(float, u);
}
__device__ __forceinline__ u8 f2f8(float f) {
  return (u8)(__builtin_amdgcn_cvt_pk_fp8_f32(f, f, 0, false) & 0xff);
}
__device__ __forceinline__ void gl_lds16(const void* g, void* l) {
  __builtin_amdgcn_global_load_lds((const __attribute__((address_space(1))) u32*)g,
                                   (__attribute__((address_space(3))) u32*)l, 16, 0, 0);
}
__device__ __forceinline__ float sigf(float x) { return 1.f / (1.f + __expf(-x)); }
__device__ __forceinline__ float tanh_(float x) { return 1.f - 2.f / (__expf(2.f * x) + 1.f); }

// ---------------- fused prep (1 launch): wih8 + WP4 + wimg bf16 + bias_a + imgmean ----------------
// blocks 0..1023: Wih; 1024..1535: WP4; 1536..1791: Wimg; 1792..1799: bias; 1800..2823: imgmean.
__global__ __launch_bounds__(256) void k_prep_all(
    const float* __restrict__ Wih_f, const float* __restrict__ Wih_b,
    const float* __restrict__ Whh_f, const float* __restrict__ Whh_b,
    const float* __restrict__ Wimg, const float* __restrict__ images,
    const float* __restrict__ bih_f, const float* __restrict__ bhh_f,
    const float* __restrict__ bih_b, const float* __restrict__ bhh_b,
    u8* __restrict__ wih8, u8* __restrict__ WP4, u16* __restrict__ wimg_bf,
    float* __restrict__ bias_a, u16* __restrict__ im_bf) {
  int bid = blockIdx.x;
  int tid = threadIdx.x;
  if (bid < 1024) {
    int dir = bid >> 9;
    int e = ((bid & 511) * 256 + tid) * 4;
    const float* W = dir ? Wih_b : Wih_f;
    float4 v = *(const float4*)(W + e);
    int w0 = __builtin_amdgcn_cvt_pk_fp8_f32(v.x * 16.f, v.y * 16.f, 0, false);
    w0 = __builtin_amdgcn_cvt_pk_fp8_f32(v.z * 16.f, v.w * 16.f, w0, true);
    *(u32*)(wih8 + (size_t)dir * 524288 + e) = (u32)w0;
  } else if (bid < 1536) {
    int i0 = ((bid - 1024) * 256 + tid) * 4;
    u8 ob[4];
#pragma unroll
    for (int d = 0; d < 4; ++d) {
      int e1 = i0 + d;
      int i = e1 & 7, l = (e1 >> 3) & 63, c = (e1 >> 9) & 1, g = (e1 >> 10) & 3;
      int s = (e1 >> 12) & 7, w = (e1 >> 15) & 7, dir = e1 >> 18;
      int h = w * 32 + c * 16 + (l & 15);
      int k = s * 32 + ((l >> 4) << 3) + i;
      const float* W = dir ? Whh_b : Whh_f;
      ob[d] = f2f8(W[(size_t)(g * 256 + h) * 256 + k] * 16.f);
    }
    *(u32*)(WP4 + i0) = (u32)ob[0] | ((u32)ob[1] << 8) | ((u32)ob[2] << 16) | ((u32)ob[3] << 24);
  } else if (bid < 1792) {
    int e = ((bid - 1536) * 256 + tid) * 4;
    float4 v = *(const float4*)(Wimg + e);
    u16x4 o;
    o.x = f2bf(v.x); o.y = f2bf(v.y); o.z = f2bf(v.z); o.w = f2bf(v.w);
    *(u16x4*)(wimg_bf + e) = o;
  } else if (bid < 1800) {
    int i = (bid - 1792) * 256 + tid;
    int dir = i >> 10, gi = i & 1023;
    bias_a[i] = dir ? (bih_b[gi] + bhh_b[gi]) : (bih_f[gi] + bhh_f[gi]);
  } else {
    int n = bid - 1800;  // 0..1023: image mean over 49 positions
    for (int j = 0; j < 2; ++j) {
      int col = tid + j * 256;
      const float* p = images + (long long)n * 49 * 512 + col;
      float s = 0.f;
      for (int r = 0; r < 49; ++r) s += p[r * 512];
      im_bf[(long long)n * 512 + col] = f2bf(s * (1.f / 49.f));
    }
  }
}

// ---------------- embedding gather + fp8 convert (x16), HW pack ----------------
__global__ __launch_bounds__(256) void k_gather8(const int* __restrict__ tok, const float* __restrict__ emb,
                                                 u8* __restrict__ x) {
  long long t = (long long)blockIdx.x * 256 + threadIdx.x;
  long long base = t * 8;
  int row = (int)(base >> 9);
  int col = (int)(base & 511);
  long long src = (long long)tok[row] * 512 + col;
  float4 a = *(const float4*)(emb + src);
  float4 b = *(const float4*)(emb + src + 4);
  int w0 = __builtin_amdgcn_cvt_pk_fp8_f32(a.x * 16.f, a.y * 16.f, 0, false);
  w0 = __builtin_amdgcn_cvt_pk_fp8_f32(a.z * 16.f, a.w * 16.f, w0, true);
  int w1 = __builtin_amdgcn_cvt_pk_fp8_f32(b.x * 16.f, b.y * 16.f, 0, false);
  w1 = __builtin_amdgcn_cvt_pk_fp8_f32(b.z * 16.f, b.w * 16.f, w1, true);
  *(u32*)(x + base) = (u32)w0;
  *(u32*)(x + base + 4) = (u32)w1;
}

// ---------------- GEMM fp8, 128x256 tile: xg = X8 @ wih8^T (x1/256) + bias -> fp8 x32, XGQ8 ----------------
// 512 blocks (64 bm x 8 bn, XCD-swizzled), 256 thr. Wave: 32 rows x 256 cols = 2x16 frags
// (acc 128 VGPR; 256-thr block -> 256-VGPR cap, no spill per r4 precedent). B re-staging 8x lower
// than the 128x128 version. Epilogue: r14-proven scattered 1B stores (wave h-contiguous, L2-merged).
__global__ __launch_bounds__(256) void k_gemm_xg10(const u8* __restrict__ X, const u8* __restrict__ W,
                                                   const float* __restrict__ bias, u8* __restrict__ XGQ) {
  __shared__ u8 Al[128 * 128];  // 16 KB
  __shared__ u8 Bl[256 * 128];  // 32 KB
  const int tid = threadIdx.x;
  const int wv = tid >> 6, lane = tid & 63;
  const int lr = lane & 15, lh = lane >> 4;
  const int bid = blockIdx.x;
  const int local = bid >> 3;
  const int bn = local & 7;
  const int bm = (bid & 7) * 8 + (local >> 3);
  f32x4 acc[2][16] = {};
  for (int kt = 0; kt < 4; ++kt) {
#pragma unroll
    for (int i = 0; i < 4; ++i) {
      int s = (i * 256 + tid) * 16;
      int row = s >> 7;
      int kb = (s & 127) ^ ((row & 7) << 4);
      gl_lds16(X + (size_t)(bm * 128 + row) * 512 + kt * 128 + kb, Al + s);
    }
#pragma unroll
    for (int i = 0; i < 8; ++i) {
      int s = (i * 256 + tid) * 16;
      int row = s >> 7;
      int kb = (s & 127) ^ ((row & 7) << 4);
      gl_lds16(W + (size_t)(bn * 256 + row) * 512 + kt * 128 + kb, Bl + s);
    }
    __syncthreads();
#pragma unroll
    for (int ks = 0; ks < 4; ++ks) {
      int off = ks * 32 + lh * 8;
      int ra = wv * 32 + lr;
      f8frag a0 = *(const f8frag*)(Al + ra * 128 + (off ^ ((ra & 7) << 4)));
      f8frag a1 = *(const f8frag*)(Al + (ra + 16) * 128 + (off ^ (((ra + 16) & 7) << 4)));
#pragma unroll
      for (int nj = 0; nj < 16; ++nj) {
        int c = nj * 16 + lr;
        f8frag b = *(const f8frag*)(Bl + c * 128 + (off ^ ((c & 7) << 4)));
        acc[0][nj] = __builtin_amdgcn_mfma_f32_16x16x32_fp8_fp8(a0, b, acc[0][nj], 0, 0, 0);
        acc[1][nj] = __builtin_amdgcn_mfma_f32_16x16x32_fp8_fp8(a1, b, acc[1][nj], 0, 0, 0);
      }
    }
    __syncthreads();
  }
  const float SD = 1.f / 256.f;
#pragma unroll
  for (int mi = 0; mi < 2; ++mi)
#pragma unroll
    for (int nj = 0; nj < 16; ++nj) {
      int col = bn * 256 + nj * 16 + lr;
      float bv = bias[col];
      int dirg = col >> 10, gg = (col >> 8) & 3, h = col & 255;
#pragma unroll
      for (int r = 0; r < 4; ++r) {
        int row = bm * 128 + wv * 32 + mi * 16 + lh * 4 + r;
        int n = row >> 6, ltok = row & 63;
        int tt = dirg ? (63 - ltok) : ltok;
        size_t idx = (((size_t)tt * 2 + dirg) * 128 + (n >> 3)) * 8192 + (size_t)(n & 7) * 1024 + h * 4 + gg;
        XGQ[idx] = f2f8((acc[mi][nj][r] * SD + bv) * 32.f);
      }
    }
}

// ---------------- image GEMM (bf16, small) ----------------
__global__ __launch_bounds__(256) void k_gemm_img(const u16* __restrict__ A, const u16* __restrict__ W,
                                                  const float* __restrict__ bias, float* __restrict__ O) {
  __shared__ u16 Al[128 * 32];
  __shared__ u16 Bl[128 * 32];
  const int tid = threadIdx.x;
  const int wv = tid >> 6, lane = tid & 63;
  const int bm = blockIdx.x, bn = blockIdx.y;
  f32x4 acc[2][8] = {};
  const int lr = lane & 15, lk = (lane >> 4) * 8;
  for (int kt = 0; kt < 16; ++kt) {
    for (int i = 0; i < 2; ++i) {
      int lin = (wv * 2 + i) * 64 + lane;
      int r = lin >> 2, kc = lin & 3;
      int k = kt * 32 + kc * 8;
      gl_lds16(A + (long long)(bm * 128 + r) * 512 + k, &Al[(wv * 2 + i) * 512]);
      gl_lds16(W + (long long)(bn * 128 + r) * 512 + k, &Bl[(wv * 2 + i) * 512]);
    }
    __syncthreads();
    bf16x8 a0 = *(const bf16x8*)&Al[(wv * 32 + lr) * 32 + lk];
    bf16x8 a1 = *(const bf16x8*)&Al[(wv * 32 + 16 + lr) * 32 + lk];
    for (int nj = 0; nj < 8; ++nj) {
      bf16x8 b = *(const bf16x8*)&Bl[(nj * 16 + lr) * 32 + lk];
      acc[0][nj] = __builtin_amdgcn_mfma_f32_16x16x32_bf16(a0, b, acc[0][nj], 0, 0, 0);
      acc[1][nj] = __builtin_amdgcn_mfma_f32_16x16x32_bf16(a1, b, acc[1][nj], 0, 0, 0);
    }
    __syncthreads();
  }
  const int lh = lane >> 4;
  for (int mi = 0; mi < 2; ++mi)
    for (int nj = 0; nj < 8; ++nj) {
      int col = bn * 128 + nj * 16 + lr;
      float bv = bias[col];
      for (int r = 0; r < 4; ++r) {
        int row = bm * 128 + wv * 32 + mi * 16 + lh * 4 + r;
        O[(long long)row * 512 + col] = acc[mi][nj][r] + bv;
      }
    }
}

// ---------------- LSTM k_lstm9: fp8 resident weights + fp8 xg stream, MFMA-zero-init ----------------
__global__ __launch_bounds__(512)
__attribute__((amdgpu_waves_per_eu(2, 2))) void k_lstm9(const u8* __restrict__ WP4,
                                                        const u8* __restrict__ XGQ,
                                                        float* __restrict__ Hf) {
  extern __shared__ char lds[];
  char* hbuf = lds + 131072;
  const int tid = threadIdx.x;
  const int w = tid >> 6, l = tid & 63;
  const int l15 = l & 15, l4 = l >> 4;
  const int b = blockIdx.x;
  const int dir = b >> 7;
  const int nblk = b & 127;
  const u8* wbase = WP4 + (size_t)dir * 262144 + (size_t)w * 32768;

#pragma unroll
  for (int j = 0; j < 16; ++j)
    gl_lds16(wbase + 16384 + j * 1024 + l * 16, lds + w * 16384 + j * 1024);
  f8frag breg[4][4][2];
#pragma unroll
  for (int s = 0; s < 4; ++s)
#pragma unroll
    for (int g = 0; g < 4; ++g)
#pragma unroll
      for (int c = 0; c < 2; ++c)
        breg[s][g][c] = *(const f8frag*)(wbase + ((s * 4 + g) * 2 + c) * 512 + l * 8);
  for (int i = tid; i < 2112; i += 512) ((u32*)hbuf)[i] = 0;
  const int xrow = (l4 & 1) * 4;
  const int hcol = w * 32 + (l4 >> 1) * 16 + l15;
  int xv[4];
  {
    const u8* xb = XGQ + (((size_t)dir) * 128 + nblk) * 8192 + hcol * 4;
#pragma unroll
    for (int r = 0; r < 4; ++r) xv[r] = *(const int*)(xb + (xrow + r) * 1024);
  }
  __syncthreads();

  float cst[4] = {0.f, 0.f, 0.f, 0.f};
  f32x4 z4 = {0.f, 0.f, 0.f, 0.f};
  asm volatile("" : "+v"(z4));  // pin zero in VGPRs
  const float S = 1.f / 512.f;
  const float SX = 1.f / 32.f;
#pragma unroll 1
  for (int t = 0; t < 64; ++t) {
    const char* hrd = hbuf + (t & 1) * 4224;
    char* hwr = hbuf + ((t + 1) & 1) * 4224;
    f32x4 acc[4][2];
    {
      f8frag a = *(const f8frag*)(hrd + l15 * 264 + l4 * 8);
#pragma unroll
      for (int g = 0; g < 4; ++g) {
        acc[g][0] = __builtin_amdgcn_mfma_f32_16x16x32_fp8_fp8(a, breg[0][g][0], z4, 0, 0, 0);
        acc[g][1] = __builtin_amdgcn_mfma_f32_16x16x32_fp8_fp8(a, breg[0][g][1], z4, 0, 0, 0);
      }
    }
#pragma unroll
    for (int s = 1; s < 4; ++s) {
      f8frag a = *(const f8frag*)(hrd + l15 * 264 + s * 32 + l4 * 8);
#pragma unroll
      for (int g = 0; g < 4; ++g) {
        acc[g][0] = __builtin_amdgcn_mfma_f32_16x16x32_fp8_fp8(a, breg[s][g][0], acc[g][0], 0, 0, 0);
        acc[g][1] = __builtin_amdgcn_mfma_f32_16x16x32_fp8_fp8(a, breg[s][g][1], acc[g][1], 0, 0, 0);
      }
    }
#pragma unroll
    for (int sl = 0; sl < 4; ++sl) {
      f8frag a = *(const f8frag*)(hrd + l15 * 264 + (4 + sl) * 32 + l4 * 8);
#pragma unroll
      for (int g = 0; g < 4; ++g)
#pragma unroll
        for (int c = 0; c < 2; ++c) {
          f8frag bb = *(const f8frag*)(lds + w * 16384 + ((sl * 4 + g) * 2 + c) * 512 + l * 8);
          acc[g][c] = __builtin_amdgcn_mfma_f32_16x16x32_fp8_fp8(a, bb, acc[g][c], 0, 0, 0);
        }
    }
#pragma unroll
    for (int r = 0; r < 4; ++r) {
      float z[4];
#pragma unroll
      for (int g = 0; g < 4; ++g) {
        u32 x = __builtin_bit_cast(u32, acc[g][0][r]);
        u32 y = __builtin_bit_cast(u32, acc[g][1][r]);
        asm("v_permlane32_swap_b32 %0, %1" : "+v"(x), "+v"(y));
        z[g] = __builtin_bit_cast(float, x);
      }
      float gi = z[0] * S + __builtin_amdgcn_cvt_f32_fp8(xv[r], 0) * SX;
      float gf = z[1] * S + __builtin_amdgcn_cvt_f32_fp8(xv[r], 1) * SX;
      float gg = z[2] * S + __builtin_amdgcn_cvt_f32_fp8(xv[r], 2) * SX;
      float go = z[3] * S + __builtin_amdgcn_cvt_f32_fp8(xv[r], 3) * SX;
      float cn = sigf(gf) * cst[r] + sigf(gi) * tanh_(gg);
      cst[r] = cn;
      float hn = sigf(go) * tanh_(cn);
      int row = xrow + r;
      if (t < 63) {
        *(u8*)(hwr + row * 264 + hcol) = f2f8(hn * 32.f);
      } else {
        Hf[(size_t)(dir * 1024 + nblk * 8 + row) * 256 + hcol] = hn;
      }
    }
    {
      int tn = (t < 63) ? t + 1 : 63;
      const u8* xb = XGQ + (((size_t)tn * 2 + dir) * 128 + nblk) * 8192 + hcol * 4;
#pragma unroll
      for (int r = 0; r < 4; ++r) xv[r] = *(const int*)(xb + (xrow + r) * 1024);
    }
    asm volatile("s_waitcnt lgkmcnt(0)" ::: "memory");
    __builtin_amdgcn_sched_barrier(0);
    __builtin_amdgcn_s_barrier();
    __builtin_amdgcn_sched_barrier(0);
  }
}

// ---------------- attention fusion + mean over tweets ----------------
__global__ __launch_bounds__(256) void k_fusion(const float* __restrict__ Hf, const float* __restrict__ IH,
                                                const float* __restrict__ WT, const float* __restrict__ WI,
                                                float* __restrict__ msum) {
  int wv = threadIdx.x >> 6, lane = threadIdx.x & 63;
  float facc[8] = {0.f, 0.f, 0.f, 0.f, 0.f, 0.f, 0.f, 0.f};
  for (int p = 0; p < 8; ++p) {
    int n = blockIdx.x * 32 + wv * 8 + p;
    float th[8], ih[8];
    float ts = 0.f, is = 0.f;
    for (int j = 0; j < 8; ++j) {
      int e = lane * 8 + j;
      float tv = (e < 256) ? Hf[(long long)n * 256 + e] : Hf[(long long)(1024 + n) * 256 + (e - 256)];
      float iv = IH[(long long)n * 512 + e];
      th[j] = tv; ih[j] = iv;
      ts += tv * WT[e];
      is += iv * WI[e];
    }
    for (int off = 32; off > 0; off >>= 1) {
      ts += __shfl_down(ts, off);
      is += __shfl_down(is, off);
    }
    ts = __shfl(ts, 0);
    is = __shfl(is, 0);
    float a0 = 1.f / (1.f + __expf(is - ts));
    float a1 = 1.f - a0;
    for (int j = 0; j < 8; ++j) facc[j] += a0 * th[j] + a1 * ih[j];
  }
  for (int j = 0; j < 8; ++j) atomicAdd(&msum[lane * 8 + j], facc[j]);
}

// ---------------- classifier MLP ----------------
__global__ __launch_bounds__(256) void k_cls(const float* __restrict__ msum, const float* __restrict__ Wc1,
                                             const float* __restrict__ bc1, const float* __restrict__ Wc2,
                                             const float* __restrict__ bc2, float* __restrict__ out) {
  __shared__ float mf[512];
  __shared__ float hdd[512];
  __shared__ float red[2][256];
  int tid = threadIdx.x;
  for (int j = tid; j < 512; j += 256) mf[j] = msum[j] * (1.f / 1024.f);
  __syncthreads();
  for (int j = tid; j < 512; j += 256) {
    const float* wr = Wc1 + (long long)j * 512;
    float s = bc1[j];
    for (int k = 0; k < 512; ++k) s += mf[k] * wr[k];
    hdd[j] = fmaxf(s, 0.f);
  }
  __syncthreads();
  float s0 = 0.f, s1 = 0.f;
  for (int k = tid; k < 512; k += 256) {
    s0 += hdd[k] * Wc2[k];
    s1 += hdd[k] * Wc2[512 + k];
  }
  red[0][tid] = s0;
  red[1][tid] = s1;
  __syncthreads();
  if (tid < 2) {
    float s = 0.f;
    for (int k = 0; k < 256; ++k) s += red[tid][k];
    out[tid] = s + bc2[tid];
  }
}

extern "C" void kernel_launch(void* const* d_in, const int* in_sizes, int n_in,
                              void* d_out, int out_size, void* d_ws, size_t ws_size,
                              hipStream_t stream) {
  const int* tokens = (const int*)d_in[0];
  const float* images = (const float*)d_in[1];
  const float* embed = (const float*)d_in[2];
  const float* Wih_f = (const float*)d_in[3];
  const float* Whh_f = (const float*)d_in[4];
  const float* bih_f = (const float*)d_in[5];
  const float* bhh_f = (const float*)d_in[6];
  const float* Wih_b = (const float*)d_in[7];
  const float* Whh_b = (const float*)d_in[8];
  const float* bih_b = (const float*)d_in[9];
  const float* bhh_b = (const float*)d_in[10];
  const float* Wimg = (const float*)d_in[11];
  const float* bimg = (const float*)d_in[12];
  const float* W_T = (const float*)d_in[13];
  const float* W_I = (const float*)d_in[14];
  const float* Wc1 = (const float*)d_in[15];
  const float* bc1 = (const float*)d_in[16];
  const float* Wc2 = (const float*)d_in[17];
  const float* bc2 = (const float*)d_in[18];
  float* out = (float*)d_out;

  char* ws = (char*)d_ws;
  size_t off = 0;
  auto alloc = [&](size_t bytes) -> void* {
    void* p = ws + off;
    off += (bytes + 255) & ~(size_t)255;
    return p;
  };
  u8* x8 = (u8*)alloc((size_t)M1 * 512);          // 32 MiB fp8 X
  u8* xgq = (u8*)alloc((size_t)M1 * 2048);        // 128 MiB fp8 XGQ (L3-resident)
  u8* wih8 = (u8*)alloc((size_t)2 * 524288);      // 1 MiB fp8 Wih (row-major)
  u8* wp = (u8*)alloc((size_t)2 * 262144);        // 512 KiB fp8 fragment-packed Whh
  u16* wimg_bf = (u16*)alloc((size_t)512 * 512 * 2);
  float* bias_a = (float*)alloc((size_t)2048 * 4);
  float* hf32 = (float*)alloc((size_t)2048 * 256 * 4);
  u16* im_bf = (u16*)alloc((size_t)1024 * 512 * 2);
  float* im_h = (float*)alloc((size_t)1024 * 512 * 4);
  float* msum = (float*)alloc((size_t)512 * 4);

  hipMemsetAsync(msum, 0, (size_t)512 * 4, stream);

  k_prep_all<<<2824, 256, 0, stream>>>(Wih_f, Wih_b, Whh_f, Whh_b, Wimg, images,
                                       bih_f, bhh_f, bih_b, bhh_b,
                                       wih8, wp, wimg_bf, bias_a, im_bf);

  k_gather8<<<16384, 256, 0, stream>>>(tokens, embed, x8);
  k_gemm_xg10<<<512, 256, 0, stream>>>(x8, wih8, bias_a, xgq);

  k_gemm_img<<<dim3(8, 4), 256, 0, stream>>>(im_bf, wimg_bf, bimg, im_h);

  hipFuncSetAttribute((const void*)k_lstm9, hipFuncAttributeMaxDynamicSharedMemorySize, 139520);
  k_lstm9<<<256, 512, 139520, stream>>>(wp, xgq, hf32);

  k_fusion<<<32, 256, 0, stream>>>(hf32, im_h, W_T, W_I, msum);
  k_cls<<<1, 256, 0, stream>>>(msum, Wc1, bc1, Wc2, bc2, out);
}